// Round 3
// baseline (1722.206 us; speedup 1.0000x reference)
//
#include <hip/hip_runtime.h>
#include <hip/hip_bf16.h>

#define N_NODES 100000
#define N_EDGES 1600000
#define D 128

// ---------------------------------------------------------------------------
// degree: deg[src] += 1 for every real edge (self loop added later as +1)
// edge_index arrives as int32 [2, E]: row 0 = src, row 1 = dst.
// ---------------------------------------------------------------------------
__global__ __launch_bounds__(256) void degree_kernel(const int* __restrict__ ei,
                                                     float* __restrict__ deg) {
    int e = blockIdx.x * 256 + threadIdx.x;
    if (e < N_EDGES) {
        int s = ei[e];  // row 0 = src
        atomicAdd(&deg[s], 1.0f);
    }
}

// dis[i] = (deg[i] + 1)^-0.5   (self loop guarantees deg>=1); in-place
__global__ __launch_bounds__(256) void rsqrt_kernel(float* __restrict__ deg) {
    int i = blockIdx.x * 256 + threadIdx.x;
    if (i < N_NODES) deg[i] = rsqrtf(deg[i] + 1.0f);
}

// ---------------------------------------------------------------------------
// GEMM: h[r][c] = b[c] + sum_k x[r][k] * W[c][k]
// Block = 256 threads, 16 rows/block. W (64KB) staged in LDS with an
// XOR-swizzled float4 layout: float4 index (c, g) stored at c*32 + (g ^ (c&7))
// so a wave's 64 lanes (consecutive c) reading group g hit all 8 bank-groups.
// x rows are read via wave-uniform global loads (L1 broadcast, row stays hot
// across the 32 k-groups). 8 rows/thread register blocking -> FMA-bound.
// ---------------------------------------------------------------------------
#define GROWS 16
__global__ __launch_bounds__(256) void gemm_kernel(const float* __restrict__ x,
                                                   const float* __restrict__ W,
                                                   const float* __restrict__ b,
                                                   float* __restrict__ h) {
    __shared__ float4 Ws[128 * 32];  // exactly 64 KiB

    const int t = threadIdx.x;
    // cooperative swizzled load of W: 4096 float4s / 256 threads = 16 each
    const float4* W4 = (const float4*)W;
#pragma unroll
    for (int i = 0; i < 16; ++i) {
        int idx = t + i * 256;          // float4 index
        int c = idx >> 5;               // W row (output col)
        int g = idx & 31;               // k-group
        Ws[c * 32 + (g ^ (c & 7))] = W4[idx];
    }
    __syncthreads();

    const int c  = t & 127;             // output column
    const int rg = t >> 7;              // 0..1 row-group
    const int row0 = blockIdx.x * GROWS + rg * 8;

    float acc[8];
    const float bc = b[c];
#pragma unroll
    for (int r = 0; r < 8; ++r) acc[r] = bc;

    const float4* xr[8];
#pragma unroll
    for (int r = 0; r < 8; ++r) xr[r] = (const float4*)(x + (size_t)(row0 + r) * D);

    for (int g = 0; g < 32; ++g) {
        float4 wv = Ws[c * 32 + (g ^ (c & 7))];
#pragma unroll
        for (int r = 0; r < 8; ++r) {
            float4 xv = xr[r][g];       // wave-uniform address -> L1 broadcast
            acc[r] += xv.x * wv.x + xv.y * wv.y + xv.z * wv.z + xv.w * wv.w;
        }
    }

#pragma unroll
    for (int r = 0; r < 8; ++r) h[(size_t)(row0 + r) * D + c] = acc[r];
}

// ---------------------------------------------------------------------------
// scatter: one wave per edge; lane l handles elements 2l, 2l+1.
// out[dst][:] += dis[src]*dis[dst] * h[src][:]
// ---------------------------------------------------------------------------
__global__ __launch_bounds__(256) void scatter_kernel(const int* __restrict__ ei,
                                                      const float* __restrict__ dis,
                                                      const float* __restrict__ h,
                                                      float* __restrict__ out) {
    int wid  = (blockIdx.x * 256 + threadIdx.x) >> 6;  // edge id
    int lane = threadIdx.x & 63;
    if (wid >= N_EDGES) return;
    int src = ei[wid];
    int dst = ei[N_EDGES + wid];
    float norm = dis[src] * dis[dst];
    float2 hv = ((const float2*)(h + (size_t)src * D))[lane];
    float* o = out + (size_t)dst * D + lane * 2;
    atomicAdd(o,     norm * hv.x);
    atomicAdd(o + 1, norm * hv.y);
}

// ---------------------------------------------------------------------------
// finalize: out = 0.125 * relu(out + dis[i]^2 * h[i])   (self-loop folded in)
// ---------------------------------------------------------------------------
__global__ __launch_bounds__(256) void finalize_kernel(const float* __restrict__ h,
                                                       const float* __restrict__ dis,
                                                       float* __restrict__ out) {
    int i = blockIdx.x * 256 + threadIdx.x;     // float4 index
    if (i >= N_NODES * (D / 4)) return;
    int row = i >> 5;
    float s = dis[row];
    s = s * s;                                   // = 1/deg
    float4 hv = ((const float4*)h)[i];
    float4 v  = ((float4*)out)[i];
    v.x = fmaxf(v.x + s * hv.x, 0.0f) * 0.125f;
    v.y = fmaxf(v.y + s * hv.y, 0.0f) * 0.125f;
    v.z = fmaxf(v.z + s * hv.z, 0.0f) * 0.125f;
    v.w = fmaxf(v.w + s * hv.w, 0.0f) * 0.125f;
    ((float4*)out)[i] = v;
}

extern "C" void kernel_launch(void* const* d_in, const int* in_sizes, int n_in,
                              void* d_out, int out_size, void* d_ws, size_t ws_size,
                              hipStream_t stream) {
    const float* x  = (const float*)d_in[0];
    const int*   ei = (const int*)d_in[1];   // [2, E] int32 (harness converts ints)
    const float* W  = (const float*)d_in[2];
    const float* b  = (const float*)d_in[3];
    float* out = (float*)d_out;

    float* h   = (float*)d_ws;            // N*D floats = 51.2 MB
    float* deg = h + (size_t)N_NODES * D; // N floats (deg, then dis in-place)

    hipMemsetAsync(deg, 0, N_NODES * sizeof(float), stream);
    hipMemsetAsync(out, 0, (size_t)N_NODES * D * sizeof(float), stream);

    degree_kernel<<<(N_EDGES + 255) / 256, 256, 0, stream>>>(ei, deg);
    gemm_kernel<<<N_NODES / GROWS, 256, 0, stream>>>(x, W, b, h);
    rsqrt_kernel<<<(N_NODES + 255) / 256, 256, 0, stream>>>(deg);

    // one wave per edge: E*64 threads = 102.4M threads, 400k blocks
    long long scatter_threads = (long long)N_EDGES * 64;
    scatter_kernel<<<(int)((scatter_threads + 255) / 256), 256, 0, stream>>>(ei, deg, h, out);

    finalize_kernel<<<(N_NODES * (D / 4) + 255) / 256, 256, 0, stream>>>(h, deg, out);
}

// Round 4
// 663.667 us; speedup vs baseline: 2.5950x; 2.5950x over previous
//
#include <hip/hip_runtime.h>
#include <hip/hip_bf16.h>

#define N_NODES 100000
#define N_EDGES 1600000
#define D 128
#define CHUNK 1024
#define NBLK ((N_NODES + CHUNK - 1) / CHUNK)   // 98

// ---------------------------------------------------------------------------
// hist: cnt_src[src]++ (for degree norm), cnt_dst[dst]++ (for CSR offsets)
// ---------------------------------------------------------------------------
__global__ __launch_bounds__(256) void hist_kernel(const int* __restrict__ ei,
                                                   int* __restrict__ cnt_src,
                                                   int* __restrict__ cnt_dst) {
    int e = blockIdx.x * 256 + threadIdx.x;
    if (e < N_EDGES) {
        atomicAdd(&cnt_src[ei[e]], 1);
        atomicAdd(&cnt_dst[ei[N_EDGES + e]], 1);
    }
}

// ---------------------------------------------------------------------------
// 3-kernel exclusive scan of cnt_dst -> off[0..N]  (chunks of 1024)
// ---------------------------------------------------------------------------
__global__ __launch_bounds__(256) void scan1_kernel(const int* __restrict__ cnt,
                                                    int* __restrict__ off,
                                                    int* __restrict__ bsum) {
    __shared__ int sh[256];
    const int t = threadIdx.x, b = blockIdx.x;
    const int base = b * CHUNK + t * 4;
    int e0 = (base + 0 < N_NODES) ? cnt[base + 0] : 0;
    int e1 = (base + 1 < N_NODES) ? cnt[base + 1] : 0;
    int e2 = (base + 2 < N_NODES) ? cnt[base + 2] : 0;
    int e3 = (base + 3 < N_NODES) ? cnt[base + 3] : 0;
    int s1 = e0, s2 = e0 + e1, s3 = e0 + e1 + e2, tsum = s3 + e3;
    sh[t] = tsum;
    __syncthreads();
    for (int o = 1; o < 256; o <<= 1) {
        int v = (t >= o) ? sh[t - o] : 0;
        __syncthreads();
        sh[t] += v;
        __syncthreads();
    }
    int tbase = (t == 0) ? 0 : sh[t - 1];
    if (base + 0 < N_NODES) off[base + 0] = tbase;
    if (base + 1 < N_NODES) off[base + 1] = tbase + s1;
    if (base + 2 < N_NODES) off[base + 2] = tbase + s2;
    if (base + 3 < N_NODES) off[base + 3] = tbase + s3;
    if (t == 255) bsum[b] = sh[255];
}

__global__ __launch_bounds__(128) void scan2_kernel(int* __restrict__ bsum,
                                                    int* __restrict__ off) {
    __shared__ int sh[128];
    const int t = threadIdx.x;
    sh[t] = (t < NBLK) ? bsum[t] : 0;
    __syncthreads();
    for (int o = 1; o < 128; o <<= 1) {
        int v = (t >= o) ? sh[t - o] : 0;
        __syncthreads();
        sh[t] += v;
        __syncthreads();
    }
    if (t < NBLK) bsum[t] = (t == 0) ? 0 : sh[t - 1];
    if (t == 0) off[N_NODES] = N_EDGES;
}

__global__ __launch_bounds__(256) void scan3_kernel(int* __restrict__ off,
                                                    const int* __restrict__ bsum) {
    const int b = blockIdx.x;
    const int base = b * CHUNK + threadIdx.x * 4;
    const int add = bsum[b];
#pragma unroll
    for (int i = 0; i < 4; ++i)
        if (base + i < N_NODES) off[base + i] += add;
}

// dis[i] = (cnt_src[i] + 1)^-0.5  (self loop adds 1)
__global__ __launch_bounds__(256) void rsqrt_kernel(const int* __restrict__ cnt_src,
                                                    float* __restrict__ dis) {
    int i = blockIdx.x * 256 + threadIdx.x;
    if (i < N_NODES) dis[i] = rsqrtf((float)cnt_src[i] + 1.0f);
}

// ---------------------------------------------------------------------------
// fill: place src into its dst-segment; reuse cnt_dst as a countdown cursor
// ---------------------------------------------------------------------------
__global__ __launch_bounds__(256) void fill_kernel(const int* __restrict__ ei,
                                                   int* __restrict__ cnt_dst,
                                                   const int* __restrict__ off,
                                                   int* __restrict__ sorted) {
    int e = blockIdx.x * 256 + threadIdx.x;
    if (e < N_EDGES) {
        int src = ei[e];
        int dst = ei[N_EDGES + e];
        int old = atomicSub(&cnt_dst[dst], 1);
        sorted[off[dst] + old - 1] = src;
    }
}

// ---------------------------------------------------------------------------
// GEMM: h[r][c] = b[c] + sum_k x[r][k] * W[c][k]   (unchanged from round 3)
// ---------------------------------------------------------------------------
#define GROWS 16
__global__ __launch_bounds__(256) void gemm_kernel(const float* __restrict__ x,
                                                   const float* __restrict__ W,
                                                   const float* __restrict__ b,
                                                   float* __restrict__ h) {
    __shared__ float4 Ws[128 * 32];  // exactly 64 KiB

    const int t = threadIdx.x;
    const float4* W4 = (const float4*)W;
#pragma unroll
    for (int i = 0; i < 16; ++i) {
        int idx = t + i * 256;
        int c = idx >> 5;
        int g = idx & 31;
        Ws[c * 32 + (g ^ (c & 7))] = W4[idx];
    }
    __syncthreads();

    const int c  = t & 127;
    const int rg = t >> 7;
    const int row0 = blockIdx.x * GROWS + rg * 8;

    float acc[8];
    const float bc = b[c];
#pragma unroll
    for (int r = 0; r < 8; ++r) acc[r] = bc;

    const float4* xr[8];
#pragma unroll
    for (int r = 0; r < 8; ++r) xr[r] = (const float4*)(x + (size_t)(row0 + r) * D);

    for (int g = 0; g < 32; ++g) {
        float4 wv = Ws[c * 32 + (g ^ (c & 7))];
#pragma unroll
        for (int r = 0; r < 8; ++r) {
            float4 xv = xr[r][g];
            acc[r] += xv.x * wv.x + xv.y * wv.y + xv.z * wv.z + xv.w * wv.w;
        }
    }

#pragma unroll
    for (int r = 0; r < 8; ++r) h[(size_t)(row0 + r) * D + c] = acc[r];
}

// ---------------------------------------------------------------------------
// gather: one wave per dst node. acc = sum_e dis[src]*h[src][:], then
// out = 0.125 * relu(dis[dst]*(acc + dis[dst]*h[dst][:]))  (self-loop fused)
// Non-atomic single write per output row.
// ---------------------------------------------------------------------------
__global__ __launch_bounds__(256) void gather_kernel(const int* __restrict__ sorted,
                                                     const int* __restrict__ off,
                                                     const float* __restrict__ dis,
                                                     const float* __restrict__ h,
                                                     float* __restrict__ out) {
    const int node = blockIdx.x * 4 + (threadIdx.x >> 6);
    const int lane = threadIdx.x & 63;
    if (node >= N_NODES) return;

    const int n0 = off[node], n1 = off[node + 1];
    float2 a0 = {0.f, 0.f}, a1 = {0.f, 0.f};
    int e = n0;
    for (; e + 2 <= n1; e += 2) {
        int s0 = sorted[e], s1 = sorted[e + 1];
        float d0 = dis[s0], d1 = dis[s1];
        float2 h0 = ((const float2*)(h + (size_t)s0 * D))[lane];
        float2 h1 = ((const float2*)(h + (size_t)s1 * D))[lane];
        a0.x = fmaf(d0, h0.x, a0.x);
        a0.y = fmaf(d0, h0.y, a0.y);
        a1.x = fmaf(d1, h1.x, a1.x);
        a1.y = fmaf(d1, h1.y, a1.y);
    }
    if (e < n1) {
        int s0 = sorted[e];
        float d0 = dis[s0];
        float2 h0 = ((const float2*)(h + (size_t)s0 * D))[lane];
        a0.x = fmaf(d0, h0.x, a0.x);
        a0.y = fmaf(d0, h0.y, a0.y);
    }
    float ax = a0.x + a1.x;
    float ay = a0.y + a1.y;

    const float dd = dis[node];
    float2 hd = ((const float2*)(h + (size_t)node * D))[lane];
    float rx = dd * fmaf(dd, hd.x, ax);
    float ry = dd * fmaf(dd, hd.y, ay);
    float2 o;
    o.x = fmaxf(rx, 0.f) * 0.125f;
    o.y = fmaxf(ry, 0.f) * 0.125f;
    ((float2*)(out + (size_t)node * D))[lane] = o;
}

extern "C" void kernel_launch(void* const* d_in, const int* in_sizes, int n_in,
                              void* d_out, int out_size, void* d_ws, size_t ws_size,
                              hipStream_t stream) {
    const float* x  = (const float*)d_in[0];
    const int*   ei = (const int*)d_in[1];   // [2, E] int32
    const float* W  = (const float*)d_in[2];
    const float* b  = (const float*)d_in[3];
    float* out = (float*)d_out;

    // workspace layout (~59 MB)
    float* h       = (float*)d_ws;                 // N*D floats (51.2 MB)
    float* dis     = h + (size_t)N_NODES * D;      // N floats
    int*   cnt_src = (int*)(dis + N_NODES);        // N ints
    int*   cnt_dst = cnt_src + N_NODES;            // N ints
    int*   off     = cnt_dst + N_NODES;            // N+1 ints
    int*   bsum    = off + N_NODES + 1;            // 128 ints
    int*   sorted  = bsum + 128;                   // E ints (6.4 MB)

    hipMemsetAsync(cnt_src, 0, N_NODES * sizeof(int), stream);
    hipMemsetAsync(cnt_dst, 0, N_NODES * sizeof(int), stream);

    hist_kernel<<<(N_EDGES + 255) / 256, 256, 0, stream>>>(ei, cnt_src, cnt_dst);
    scan1_kernel<<<NBLK, 256, 0, stream>>>(cnt_dst, off, bsum);
    scan2_kernel<<<1, 128, 0, stream>>>(bsum, off);
    scan3_kernel<<<NBLK, 256, 0, stream>>>(off, bsum);
    rsqrt_kernel<<<(N_NODES + 255) / 256, 256, 0, stream>>>(cnt_src, dis);
    fill_kernel<<<(N_EDGES + 255) / 256, 256, 0, stream>>>(ei, cnt_dst, off, sorted);

    gemm_kernel<<<N_NODES / GROWS, 256, 0, stream>>>(x, W, b, h);

    gather_kernel<<<(N_NODES + 3) / 4, 256, 0, stream>>>(sorted, off, dis, h, out);
}

// Round 5
// 638.239 us; speedup vs baseline: 2.6984x; 1.0398x over previous
//
#include <hip/hip_runtime.h>
#include <hip/hip_bf16.h>

#define N_NODES 100000
#define N_EDGES 1600000
#define D 128
#define CHUNK 1024
#define NBLK ((N_NODES + CHUNK - 1) / CHUNK)   // 98

// ---------------------------------------------------------------------------
// hist: cnt_src[src]++ (degree norm), cnt_dst[dst]++ (CSR offsets)
// ---------------------------------------------------------------------------
__global__ __launch_bounds__(256) void hist_kernel(const int* __restrict__ ei,
                                                   int* __restrict__ cnt_src,
                                                   int* __restrict__ cnt_dst) {
    int e = blockIdx.x * 256 + threadIdx.x;
    if (e < N_EDGES) {
        atomicAdd(&cnt_src[ei[e]], 1);
        atomicAdd(&cnt_dst[ei[N_EDGES + e]], 1);
    }
}

// ---------------------------------------------------------------------------
// 3-kernel exclusive scan of cnt_dst -> off[0..N]
// ---------------------------------------------------------------------------
__global__ __launch_bounds__(256) void scan1_kernel(const int* __restrict__ cnt,
                                                    int* __restrict__ off,
                                                    int* __restrict__ bsum) {
    __shared__ int sh[256];
    const int t = threadIdx.x, b = blockIdx.x;
    const int base = b * CHUNK + t * 4;
    int e0 = (base + 0 < N_NODES) ? cnt[base + 0] : 0;
    int e1 = (base + 1 < N_NODES) ? cnt[base + 1] : 0;
    int e2 = (base + 2 < N_NODES) ? cnt[base + 2] : 0;
    int e3 = (base + 3 < N_NODES) ? cnt[base + 3] : 0;
    int s1 = e0, s2 = e0 + e1, s3 = e0 + e1 + e2, tsum = s3 + e3;
    sh[t] = tsum;
    __syncthreads();
    for (int o = 1; o < 256; o <<= 1) {
        int v = (t >= o) ? sh[t - o] : 0;
        __syncthreads();
        sh[t] += v;
        __syncthreads();
    }
    int tbase = (t == 0) ? 0 : sh[t - 1];
    if (base + 0 < N_NODES) off[base + 0] = tbase;
    if (base + 1 < N_NODES) off[base + 1] = tbase + s1;
    if (base + 2 < N_NODES) off[base + 2] = tbase + s2;
    if (base + 3 < N_NODES) off[base + 3] = tbase + s3;
    if (t == 255) bsum[b] = sh[255];
}

__global__ __launch_bounds__(128) void scan2_kernel(int* __restrict__ bsum,
                                                    int* __restrict__ off) {
    __shared__ int sh[128];
    const int t = threadIdx.x;
    sh[t] = (t < NBLK) ? bsum[t] : 0;
    __syncthreads();
    for (int o = 1; o < 128; o <<= 1) {
        int v = (t >= o) ? sh[t - o] : 0;
        __syncthreads();
        sh[t] += v;
        __syncthreads();
    }
    if (t < NBLK) bsum[t] = (t == 0) ? 0 : sh[t - 1];
    if (t == 0) off[N_NODES] = N_EDGES;
}

__global__ __launch_bounds__(256) void scan3_kernel(int* __restrict__ off,
                                                    const int* __restrict__ bsum) {
    const int b = blockIdx.x;
    const int base = b * CHUNK + threadIdx.x * 4;
    const int add = bsum[b];
#pragma unroll
    for (int i = 0; i < 4; ++i)
        if (base + i < N_NODES) off[base + i] += add;
}

// dis[i] = (cnt_src[i] + 1)^-0.5  (self loop adds 1)
__global__ __launch_bounds__(256) void rsqrt_kernel(const int* __restrict__ cnt_src,
                                                    float* __restrict__ dis) {
    int i = blockIdx.x * 256 + threadIdx.x;
    if (i < N_NODES) dis[i] = rsqrtf((float)cnt_src[i] + 1.0f);
}

// ---------------------------------------------------------------------------
// fill: place src into its dst-segment; cnt_dst reused as countdown cursor
// ---------------------------------------------------------------------------
__global__ __launch_bounds__(256) void fill_kernel(const int* __restrict__ ei,
                                                   int* __restrict__ cnt_dst,
                                                   const int* __restrict__ off,
                                                   int* __restrict__ sorted) {
    int e = blockIdx.x * 256 + threadIdx.x;
    if (e < N_EDGES) {
        int src = ei[e];
        int dst = ei[N_EDGES + e];
        int old = atomicSub(&cnt_dst[dst], 1);
        sorted[off[dst] + old - 1] = src;
    }
}

// ---------------------------------------------------------------------------
// GEMM: h[r][c] = dis[r] * (b[c] + sum_k x[r][k] * W[c][k])   (pre-scaled!)
// Tile: 32 rows x 64 cols, 256 threads (4 waves; wave = 64 cols, 8 rows).
// W half-tile (32KB) in LDS, g-major layout Ws[g*64+c]: main-loop ds_read
// is 64 lanes x 16B contiguous = conflict-free. x prefetched into regs
// (unroll-2 ping-pong) so L2 latency overlaps FMAs. ~5 blocks/CU.
// ---------------------------------------------------------------------------
#define GEMM_ROWS 32
__global__ __launch_bounds__(256) void gemm_kernel(const float* __restrict__ x,
                                                   const float* __restrict__ W,
                                                   const float* __restrict__ bias,
                                                   const float* __restrict__ dis,
                                                   float* __restrict__ h) {
    __shared__ float4 Ws[32 * 64];  // 32 KiB

    const int t = threadIdx.x;
    const int c0 = blockIdx.y * 64;
    const float4* W4 = (const float4*)W;  // [128][32] float4 row-major
#pragma unroll
    for (int i = 0; i < 8; ++i) {
        int j = i * 256 + t;              // 0..2047, global-coalesced read
        int c = j >> 5;                   // col within tile
        int g = j & 31;                   // k-group
        Ws[g * 64 + c] = W4[(size_t)(c0 + c) * 32 + g];
    }
    __syncthreads();

    const int cl  = t & 63;
    const int rg  = t >> 6;               // 0..3
    const int row0 = blockIdx.x * GEMM_ROWS + rg * 8;
    const float4* xb = (const float4*)(x + (size_t)row0 * D);  // row r -> r*32+g

    float acc[8];
    const float bc = bias[c0 + cl];
#pragma unroll
    for (int r = 0; r < 8; ++r) acc[r] = bc;

    float4 xa[8], xp[8];
#pragma unroll
    for (int r = 0; r < 8; ++r) xa[r] = xb[r * 32];

    for (int g = 0; g < 32; g += 2) {
        float4 wv0 = Ws[g * 64 + cl];
#pragma unroll
        for (int r = 0; r < 8; ++r) xp[r] = xb[r * 32 + g + 1];
#pragma unroll
        for (int r = 0; r < 8; ++r) {
            acc[r] = fmaf(xa[r].x, wv0.x, acc[r]);
            acc[r] = fmaf(xa[r].y, wv0.y, acc[r]);
            acc[r] = fmaf(xa[r].z, wv0.z, acc[r]);
            acc[r] = fmaf(xa[r].w, wv0.w, acc[r]);
        }
        float4 wv1 = Ws[(g + 1) * 64 + cl];
        if (g + 2 < 32) {
#pragma unroll
            for (int r = 0; r < 8; ++r) xa[r] = xb[r * 32 + g + 2];
        }
#pragma unroll
        for (int r = 0; r < 8; ++r) {
            acc[r] = fmaf(xp[r].x, wv1.x, acc[r]);
            acc[r] = fmaf(xp[r].y, wv1.y, acc[r]);
            acc[r] = fmaf(xp[r].z, wv1.z, acc[r]);
            acc[r] = fmaf(xp[r].w, wv1.w, acc[r]);
        }
    }

#pragma unroll
    for (int r = 0; r < 8; ++r)
        h[(size_t)(row0 + r) * D + c0 + cl] = dis[row0 + r] * acc[r];
}

// ---------------------------------------------------------------------------
// gather: one wave per dst node; h is pre-scaled by dis[src], so the inner
// loop is a pure row-sum. out = 0.125*relu(dis[dst]*(sum + h'[dst])).
// Unroll-4: 4 independent 512B row reads in flight.
// ---------------------------------------------------------------------------
__global__ __launch_bounds__(256) void gather_kernel(const int* __restrict__ sorted,
                                                     const int* __restrict__ off,
                                                     const float* __restrict__ dis,
                                                     const float* __restrict__ h,
                                                     float* __restrict__ out) {
    const int node = blockIdx.x * 4 + (threadIdx.x >> 6);
    const int lane = threadIdx.x & 63;
    if (node >= N_NODES) return;

    const int n0 = off[node], n1 = off[node + 1];
    float2 a0 = {0.f, 0.f}, a1 = {0.f, 0.f}, a2 = {0.f, 0.f}, a3 = {0.f, 0.f};
    int e = n0;
    for (; e + 4 <= n1; e += 4) {
        int s0 = sorted[e], s1 = sorted[e + 1], s2 = sorted[e + 2], s3 = sorted[e + 3];
        float2 h0 = ((const float2*)(h + (size_t)s0 * D))[lane];
        float2 h1 = ((const float2*)(h + (size_t)s1 * D))[lane];
        float2 h2 = ((const float2*)(h + (size_t)s2 * D))[lane];
        float2 h3 = ((const float2*)(h + (size_t)s3 * D))[lane];
        a0.x += h0.x; a0.y += h0.y;
        a1.x += h1.x; a1.y += h1.y;
        a2.x += h2.x; a2.y += h2.y;
        a3.x += h3.x; a3.y += h3.y;
    }
    for (; e < n1; ++e) {
        int s0 = sorted[e];
        float2 h0 = ((const float2*)(h + (size_t)s0 * D))[lane];
        a0.x += h0.x; a0.y += h0.y;
    }
    float ax = (a0.x + a1.x) + (a2.x + a3.x);
    float ay = (a0.y + a1.y) + (a2.y + a3.y);

    const float dd = dis[node];
    float2 hd = ((const float2*)(h + (size_t)node * D))[lane];
    float rx = dd * (ax + hd.x);
    float ry = dd * (ay + hd.y);
    float2 o;
    o.x = fmaxf(rx, 0.f) * 0.125f;
    o.y = fmaxf(ry, 0.f) * 0.125f;
    ((float2*)(out + (size_t)node * D))[lane] = o;
}

extern "C" void kernel_launch(void* const* d_in, const int* in_sizes, int n_in,
                              void* d_out, int out_size, void* d_ws, size_t ws_size,
                              hipStream_t stream) {
    const float* x  = (const float*)d_in[0];
    const int*   ei = (const int*)d_in[1];   // [2, E] int32
    const float* W  = (const float*)d_in[2];
    const float* b  = (const float*)d_in[3];
    float* out = (float*)d_out;

    float* h       = (float*)d_ws;                 // N*D floats (51.2 MB)
    float* dis     = h + (size_t)N_NODES * D;      // N floats
    int*   cnt_src = (int*)(dis + N_NODES);        // N ints
    int*   cnt_dst = cnt_src + N_NODES;            // N ints
    int*   off     = cnt_dst + N_NODES;            // N+1 ints
    int*   bsum    = off + N_NODES + 1;            // 128 ints
    int*   sorted  = bsum + 128;                   // E ints (6.4 MB)

    hipMemsetAsync(cnt_src, 0, N_NODES * sizeof(int), stream);
    hipMemsetAsync(cnt_dst, 0, N_NODES * sizeof(int), stream);

    hist_kernel<<<(N_EDGES + 255) / 256, 256, 0, stream>>>(ei, cnt_src, cnt_dst);
    scan1_kernel<<<NBLK, 256, 0, stream>>>(cnt_dst, off, bsum);
    scan2_kernel<<<1, 128, 0, stream>>>(bsum, off);
    scan3_kernel<<<NBLK, 256, 0, stream>>>(off, bsum);
    rsqrt_kernel<<<(N_NODES + 255) / 256, 256, 0, stream>>>(cnt_src, dis);
    fill_kernel<<<(N_EDGES + 255) / 256, 256, 0, stream>>>(ei, cnt_dst, off, sorted);

    dim3 ggrid(N_NODES / GEMM_ROWS, 2);
    gemm_kernel<<<ggrid, 256, 0, stream>>>(x, W, b, dis, h);

    gather_kernel<<<(N_NODES + 3) / 4, 256, 0, stream>>>(sorted, off, dis, h, out);
}

// Round 6
// 497.193 us; speedup vs baseline: 3.4639x; 1.2837x over previous
//
#include <hip/hip_runtime.h>
#include <hip/hip_bf16.h>

#define N_NODES 100000
#define N_EDGES 1600000
#define D 128
#define CHUNK 1024
#define NBLK ((N_NODES + CHUNK - 1) / CHUNK)   // 98

// ---------------------------------------------------------------------------
// hist: cnt_src[src]++ (degree norm), cnt_dst[dst]++ (CSR offsets)
// ---------------------------------------------------------------------------
__global__ __launch_bounds__(256) void hist_kernel(const int* __restrict__ ei,
                                                   int* __restrict__ cnt_src,
                                                   int* __restrict__ cnt_dst) {
    int e = blockIdx.x * 256 + threadIdx.x;
    if (e < N_EDGES) {
        atomicAdd(&cnt_src[ei[e]], 1);
        atomicAdd(&cnt_dst[ei[N_EDGES + e]], 1);
    }
}

// ---------------------------------------------------------------------------
// scan1: per-chunk exclusive scan of cnt_dst -> off, chunk sums -> bsum.
// Also fused: dis[i] = rsqrt(cnt_src[i] + 1)  (self loop adds 1).
// ---------------------------------------------------------------------------
__global__ __launch_bounds__(256) void scan1_kernel(const int* __restrict__ cnt,
                                                    const int* __restrict__ cnt_src,
                                                    float* __restrict__ dis,
                                                    int* __restrict__ off,
                                                    int* __restrict__ bsum) {
    __shared__ int sh[256];
    const int t = threadIdx.x, b = blockIdx.x;
    const int base = b * CHUNK + t * 4;
#pragma unroll
    for (int i = 0; i < 4; ++i)
        if (base + i < N_NODES) dis[base + i] = rsqrtf((float)cnt_src[base + i] + 1.0f);
    int e0 = (base + 0 < N_NODES) ? cnt[base + 0] : 0;
    int e1 = (base + 1 < N_NODES) ? cnt[base + 1] : 0;
    int e2 = (base + 2 < N_NODES) ? cnt[base + 2] : 0;
    int e3 = (base + 3 < N_NODES) ? cnt[base + 3] : 0;
    int s1 = e0, s2 = e0 + e1, s3 = e0 + e1 + e2, tsum = s3 + e3;
    sh[t] = tsum;
    __syncthreads();
    for (int o = 1; o < 256; o <<= 1) {
        int v = (t >= o) ? sh[t - o] : 0;
        __syncthreads();
        sh[t] += v;
        __syncthreads();
    }
    int tbase = (t == 0) ? 0 : sh[t - 1];
    if (base + 0 < N_NODES) off[base + 0] = tbase;
    if (base + 1 < N_NODES) off[base + 1] = tbase + s1;
    if (base + 2 < N_NODES) off[base + 2] = tbase + s2;
    if (base + 3 < N_NODES) off[base + 3] = tbase + s3;
    if (t == 255) bsum[b] = sh[255];
}

__global__ __launch_bounds__(128) void scan2_kernel(int* __restrict__ bsum,
                                                    int* __restrict__ off) {
    __shared__ int sh[128];
    const int t = threadIdx.x;
    sh[t] = (t < NBLK) ? bsum[t] : 0;
    __syncthreads();
    for (int o = 1; o < 128; o <<= 1) {
        int v = (t >= o) ? sh[t - o] : 0;
        __syncthreads();
        sh[t] += v;
        __syncthreads();
    }
    if (t < NBLK) bsum[t] = (t == 0) ? 0 : sh[t - 1];
    if (t == 0) off[N_NODES] = N_EDGES;
}

__global__ __launch_bounds__(256) void scan3_kernel(int* __restrict__ off,
                                                    const int* __restrict__ bsum) {
    const int b = blockIdx.x;
    const int base = b * CHUNK + threadIdx.x * 4;
    const int add = bsum[b];
#pragma unroll
    for (int i = 0; i < 4; ++i)
        if (base + i < N_NODES) off[base + i] += add;
}

// ---------------------------------------------------------------------------
// fill: place src into its dst-segment; cnt_dst reused as countdown cursor
// ---------------------------------------------------------------------------
__global__ __launch_bounds__(256) void fill_kernel(const int* __restrict__ ei,
                                                   int* __restrict__ cnt_dst,
                                                   const int* __restrict__ off,
                                                   int* __restrict__ sorted) {
    int e = blockIdx.x * 256 + threadIdx.x;
    if (e < N_EDGES) {
        int src = ei[e];
        int dst = ei[N_EDGES + e];
        int old = atomicSub(&cnt_dst[dst], 1);
        sorted[off[dst] + old - 1] = src;
    }
}

// ---------------------------------------------------------------------------
// GEMM v3: h[r][c] = dis[r] * (b[c] + sum_k x[r][k] * W[c][k])
// Both operands in LDS. BM=32 rows x all 128 cols, 256 threads, 4x4 register
// blocking. XOR swizzle kg^((row>>2)&7) on both tiles: every compute read's 8
// distinct addresses hit 8 distinct 16B bank-groups (addr/16 mod 8 distinct),
// the 8 lanes sharing an address broadcast. 80 KB LDS -> 2 blocks/CU.
// ---------------------------------------------------------------------------
#define BM 32
__global__ __launch_bounds__(256) void gemm_kernel(const float* __restrict__ x,
                                                   const float* __restrict__ W,
                                                   const float* __restrict__ bias,
                                                   const float* __restrict__ dis,
                                                   float* __restrict__ h) {
    __shared__ float4 Ws[128 * 32];  // 64 KiB
    __shared__ float4 Xs[32 * 32];   // 16 KiB

    const int t = threadIdx.x;
    const float4* W4 = (const float4*)W;       // [128 c][32 kg]
#pragma unroll
    for (int i = 0; i < 16; ++i) {
        int j = i * 256 + t;                   // coalesced
        int c = j >> 5, kg = j & 31;
        Ws[c * 32 + (kg ^ ((c >> 2) & 7))] = W4[j];
    }
    const int row0 = blockIdx.x * BM;
    const float4* X4 = (const float4*)(x + (size_t)row0 * D);
#pragma unroll
    for (int i = 0; i < 4; ++i) {
        int j = i * 256 + t;                   // coalesced 16 KB
        int r = j >> 5, kg = j & 31;
        Xs[r * 32 + (kg ^ ((r >> 2) & 7))] = X4[j];
    }
    __syncthreads();

    const int rg = t & 7;    // rows rg*4 .. rg*4+3   ((row>>2)&7 == rg)
    const int cg = t >> 3;   // cols cg*4 .. cg*4+3   ((col>>2)&7 == cg&7)
    const int xswz = rg;
    const int wswz = cg & 7;

    float acc[4][4];
#pragma unroll
    for (int a = 0; a < 4; ++a)
#pragma unroll
        for (int c2 = 0; c2 < 4; ++c2) acc[a][c2] = 0.f;

#pragma unroll 2
    for (int kg = 0; kg < 32; ++kg) {
        float4 xv[4], wv[4];
#pragma unroll
        for (int ri = 0; ri < 4; ++ri)
            xv[ri] = Xs[(rg * 4 + ri) * 32 + (kg ^ xswz)];
#pragma unroll
        for (int ci = 0; ci < 4; ++ci)
            wv[ci] = Ws[(cg * 4 + ci) * 32 + (kg ^ wswz)];
#pragma unroll
        for (int ri = 0; ri < 4; ++ri)
#pragma unroll
            for (int ci = 0; ci < 4; ++ci) {
                acc[ri][ci] = fmaf(xv[ri].x, wv[ci].x, acc[ri][ci]);
                acc[ri][ci] = fmaf(xv[ri].y, wv[ci].y, acc[ri][ci]);
                acc[ri][ci] = fmaf(xv[ri].z, wv[ci].z, acc[ri][ci]);
                acc[ri][ci] = fmaf(xv[ri].w, wv[ci].w, acc[ri][ci]);
            }
    }

    const float4 bv = ((const float4*)bias)[cg];
#pragma unroll
    for (int ri = 0; ri < 4; ++ri) {
        int row = row0 + rg * 4 + ri;
        float dv = dis[row];
        float4 o;
        o.x = dv * (acc[ri][0] + bv.x);
        o.y = dv * (acc[ri][1] + bv.y);
        o.z = dv * (acc[ri][2] + bv.z);
        o.w = dv * (acc[ri][3] + bv.w);
        ((float4*)(h + (size_t)row * D))[cg] = o;
    }
}

// ---------------------------------------------------------------------------
// gather v2: one wave per dst node; float4/lane, half-wave row pairing:
// lanes 0-31 read row e, lanes 32-63 read row e+1 in ONE instruction.
// 4 paired loads in flight = 8 edges. Cross-half shfl_xor(32) reduce, then
// out = 0.125*relu(dis[dst]*(sum + h'[dst])), half-wave float4 write.
// ---------------------------------------------------------------------------
__global__ __launch_bounds__(256) void gather_kernel(const int* __restrict__ sorted,
                                                     const int* __restrict__ off,
                                                     const float* __restrict__ dis,
                                                     const float* __restrict__ h,
                                                     float* __restrict__ out) {
    const int node = blockIdx.x * 4 + (threadIdx.x >> 6);
    const int lane = threadIdx.x & 63;
    if (node >= N_NODES) return;
    const int half = lane >> 5;
    const int l32  = lane & 31;

    const int n0 = off[node], n1 = off[node + 1];
    float4 a0 = {0,0,0,0}, a1 = {0,0,0,0}, a2 = {0,0,0,0}, a3 = {0,0,0,0};
    int e = n0;
    for (; e + 8 <= n1; e += 8) {
        int s0 = sorted[e + 0 + half];
        int s1 = sorted[e + 2 + half];
        int s2 = sorted[e + 4 + half];
        int s3 = sorted[e + 6 + half];
        float4 v0 = ((const float4*)(h + (size_t)s0 * D))[l32];
        float4 v1 = ((const float4*)(h + (size_t)s1 * D))[l32];
        float4 v2 = ((const float4*)(h + (size_t)s2 * D))[l32];
        float4 v3 = ((const float4*)(h + (size_t)s3 * D))[l32];
        a0.x += v0.x; a0.y += v0.y; a0.z += v0.z; a0.w += v0.w;
        a1.x += v1.x; a1.y += v1.y; a1.z += v1.z; a1.w += v1.w;
        a2.x += v2.x; a2.y += v2.y; a2.z += v2.z; a2.w += v2.w;
        a3.x += v3.x; a3.y += v3.y; a3.z += v3.z; a3.w += v3.w;
    }
    for (; e + 2 <= n1; e += 2) {
        int s = sorted[e + half];
        float4 v = ((const float4*)(h + (size_t)s * D))[l32];
        a0.x += v.x; a0.y += v.y; a0.z += v.z; a0.w += v.w;
    }
    if (e < n1) {  // one leftover edge: low half only
        int s = sorted[e];
        float4 v = ((const float4*)(h + (size_t)s * D))[l32];
        if (half == 0) {
            a0.x += v.x; a0.y += v.y; a0.z += v.z; a0.w += v.w;
        }
    }
    float4 tot;
    tot.x = (a0.x + a1.x) + (a2.x + a3.x);
    tot.y = (a0.y + a1.y) + (a2.y + a3.y);
    tot.z = (a0.z + a1.z) + (a2.z + a3.z);
    tot.w = (a0.w + a1.w) + (a2.w + a3.w);
    tot.x += __shfl_xor(tot.x, 32);
    tot.y += __shfl_xor(tot.y, 32);
    tot.z += __shfl_xor(tot.z, 32);
    tot.w += __shfl_xor(tot.w, 32);

    if (half == 0) {
        const float dd = dis[node];
        float4 hd = ((const float4*)(h + (size_t)node * D))[l32];
        float4 o;
        o.x = fmaxf(dd * (tot.x + hd.x), 0.f) * 0.125f;
        o.y = fmaxf(dd * (tot.y + hd.y), 0.f) * 0.125f;
        o.z = fmaxf(dd * (tot.z + hd.z), 0.f) * 0.125f;
        o.w = fmaxf(dd * (tot.w + hd.w), 0.f) * 0.125f;
        ((float4*)(out + (size_t)node * D))[l32] = o;
    }
}

extern "C" void kernel_launch(void* const* d_in, const int* in_sizes, int n_in,
                              void* d_out, int out_size, void* d_ws, size_t ws_size,
                              hipStream_t stream) {
    const float* x  = (const float*)d_in[0];
    const int*   ei = (const int*)d_in[1];   // [2, E] int32
    const float* W  = (const float*)d_in[2];
    const float* b  = (const float*)d_in[3];
    float* out = (float*)d_out;

    float* h       = (float*)d_ws;                 // N*D floats (51.2 MB)
    float* dis     = h + (size_t)N_NODES * D;      // N floats
    int*   cnt_src = (int*)(dis + N_NODES);        // N ints
    int*   cnt_dst = cnt_src + N_NODES;            // N ints
    int*   off     = cnt_dst + N_NODES;            // N+1 ints
    int*   bsum    = off + N_NODES + 1;            // 128 ints
    int*   sorted  = bsum + 128;                   // E ints (6.4 MB)

    hipMemsetAsync(cnt_src, 0, N_NODES * sizeof(int), stream);
    hipMemsetAsync(cnt_dst, 0, N_NODES * sizeof(int), stream);

    hist_kernel<<<(N_EDGES + 255) / 256, 256, 0, stream>>>(ei, cnt_src, cnt_dst);
    scan1_kernel<<<NBLK, 256, 0, stream>>>(cnt_dst, cnt_src, dis, off, bsum);
    scan2_kernel<<<1, 128, 0, stream>>>(bsum, off);
    scan3_kernel<<<NBLK, 256, 0, stream>>>(off, bsum);
    fill_kernel<<<(N_EDGES + 255) / 256, 256, 0, stream>>>(ei, cnt_dst, off, sorted);

    gemm_kernel<<<N_NODES / BM, 256, 0, stream>>>(x, W, b, dis, h);

    gather_kernel<<<(N_NODES + 3) / 4, 256, 0, stream>>>(sorted, off, dis, h, out);
}

// Round 7
// 351.589 us; speedup vs baseline: 4.8984x; 1.4141x over previous
//
#include <hip/hip_runtime.h>
#include <hip/hip_bf16.h>

#define N_NODES 100000
#define N_EDGES 1600000
#define D 128
#define NBUK 391                 // ceil(N_NODES / 256); bucket = 256 nodes
#define EPB 8192                 // edges per block in binning passes
#define NB_E ((N_EDGES + EPB - 1) / EPB)   // 196

// ---------------------------------------------------------------------------
// bin_count: per-block LDS histograms of src/dst BUCKET (node>>8), flushed
// with one global atomic per (block,bucket). 153K global atomics total
// (vs 3.2M random ones in the old hist) -> avoids the 32B/atomic HBM tax.
// ---------------------------------------------------------------------------
__global__ __launch_bounds__(256) void bin_count_kernel(const int* __restrict__ ei,
                                                        int* __restrict__ bukcnt_d,
                                                        int* __restrict__ bukcnt_s) {
    __shared__ int cd[NBUK], cs[NBUK];
    const int t = threadIdx.x;
    for (int b = t; b < NBUK; b += 256) { cd[b] = 0; cs[b] = 0; }
    __syncthreads();
    const int e0 = blockIdx.x * EPB;
#pragma unroll
    for (int i = 0; i < EPB / 256; ++i) {
        int e = e0 + i * 256 + t;
        if (e < N_EDGES) {
            atomicAdd(&cs[ei[e] >> 8], 1);
            atomicAdd(&cd[ei[N_EDGES + e] >> 8], 1);
        }
    }
    __syncthreads();
    for (int b = t; b < NBUK; b += 256) {
        if (cd[b]) atomicAdd(&bukcnt_d[b], cd[b]);
        if (cs[b]) atomicAdd(&bukcnt_s[b], cs[b]);
    }
}

// ---------------------------------------------------------------------------
// bukscan: single-block exclusive scan of both 391-entry bucket-count arrays;
// initializes the reservation cursors; sets off[N] = E.
// ---------------------------------------------------------------------------
__global__ __launch_bounds__(512) void bukscan_kernel(const int* __restrict__ bukcnt_d,
                                                      const int* __restrict__ bukcnt_s,
                                                      int* __restrict__ bukoff_d,
                                                      int* __restrict__ bukoff_s,
                                                      int* __restrict__ bukcur_d,
                                                      int* __restrict__ bukcur_s,
                                                      int* __restrict__ off) {
    __shared__ int sd[512], ss[512];
    const int t = threadIdx.x;
    sd[t] = (t < NBUK) ? bukcnt_d[t] : 0;
    ss[t] = (t < NBUK) ? bukcnt_s[t] : 0;
    __syncthreads();
    for (int o = 1; o < 512; o <<= 1) {
        int vd = (t >= o) ? sd[t - o] : 0;
        int vs = (t >= o) ? ss[t - o] : 0;
        __syncthreads();
        sd[t] += vd; ss[t] += vs;
        __syncthreads();
    }
    if (t <= NBUK) {
        int od = (t == 0) ? 0 : sd[t - 1];
        int os = (t == 0) ? 0 : ss[t - 1];
        bukoff_d[t] = od;
        bukoff_s[t] = os;
        if (t < NBUK) { bukcur_d[t] = od; bukcur_s[t] = os; }
    }
    if (t == 0) off[N_NODES] = N_EDGES;
}

// ---------------------------------------------------------------------------
// bin_scatter: recount locally, reserve contiguous per-bucket ranges with ONE
// global atomic per (block,bucket), then write edges into their bucket bins.
// dstbin entry packs (src<<8)|dst_local (17+8=25 bits). srcbin stores the
// src_local byte (all the src-side histogram needs).
// ---------------------------------------------------------------------------
__global__ __launch_bounds__(256) void bin_scatter_kernel(const int* __restrict__ ei,
                                                          int* __restrict__ bukcur_d,
                                                          int* __restrict__ bukcur_s,
                                                          unsigned int* __restrict__ dstbin,
                                                          unsigned char* __restrict__ srcbin) {
    __shared__ int cd[NBUK], cs[NBUK];
    __shared__ int bd[NBUK], bs[NBUK];
    const int t = threadIdx.x;
    for (int b = t; b < NBUK; b += 256) { cd[b] = 0; cs[b] = 0; }
    __syncthreads();
    const int e0 = blockIdx.x * EPB;
#pragma unroll
    for (int i = 0; i < EPB / 256; ++i) {
        int e = e0 + i * 256 + t;
        if (e < N_EDGES) {
            atomicAdd(&cs[ei[e] >> 8], 1);
            atomicAdd(&cd[ei[N_EDGES + e] >> 8], 1);
        }
    }
    __syncthreads();
    for (int b = t; b < NBUK; b += 256) {
        bd[b] = cd[b] ? atomicAdd(&bukcur_d[b], cd[b]) : 0;
        bs[b] = cs[b] ? atomicAdd(&bukcur_s[b], cs[b]) : 0;
        cd[b] = 0; cs[b] = 0;
    }
    __syncthreads();
#pragma unroll
    for (int i = 0; i < EPB / 256; ++i) {
        int e = e0 + i * 256 + t;
        if (e < N_EDGES) {
            int s = ei[e];
            int d = ei[N_EDGES + e];
            int p1 = bd[d >> 8] + atomicAdd(&cd[d >> 8], 1);
            dstbin[p1] = ((unsigned)s << 8) | (unsigned)(d & 255);
            int p2 = bs[s >> 8] + atomicAdd(&cs[s >> 8], 1);
            srcbin[p2] = (unsigned char)(s & 255);
        }
    }
}

// ---------------------------------------------------------------------------
// bucket_build: one block per bucket (256 nodes). dst side: LDS 256-bin
// histogram -> LDS exclusive scan -> off[], then LDS-cursor scatter of src
// values into sorted[] (writes land in this bucket's contiguous region).
// src side: LDS histogram -> dis[node] = rsqrt(cnt+1) directly.
// ---------------------------------------------------------------------------
__global__ __launch_bounds__(256) void bucket_build_kernel(const unsigned int* __restrict__ dstbin,
                                                           const unsigned char* __restrict__ srcbin,
                                                           const int* __restrict__ bukoff_d,
                                                           const int* __restrict__ bukoff_s,
                                                           int* __restrict__ off,
                                                           int* __restrict__ sorted,
                                                           float* __restrict__ dis) {
    __shared__ int hist[256];
    __shared__ int scn[256];
    __shared__ int cur[256];
    const int t = threadIdx.x, b = blockIdx.x;
    const int node = b * 256 + t;

    // ---- dst side: per-node offsets + scatter ----
    const int s0 = bukoff_d[b], s1 = bukoff_d[b + 1];
    hist[t] = 0;
    __syncthreads();
    for (int i = s0 + t; i < s1; i += 256) atomicAdd(&hist[dstbin[i] & 255], 1);
    __syncthreads();
    scn[t] = hist[t];
    __syncthreads();
    for (int o = 1; o < 256; o <<= 1) {
        int v = (t >= o) ? scn[t - o] : 0;
        __syncthreads();
        scn[t] += v;
        __syncthreads();
    }
    const int mybase = s0 + ((t == 0) ? 0 : scn[t - 1]);
    if (node < N_NODES) off[node] = mybase;
    cur[t] = mybase;
    __syncthreads();
    for (int i = s0 + t; i < s1; i += 256) {
        unsigned p = dstbin[i];
        int pos = atomicAdd(&cur[p & 255], 1);
        sorted[pos] = (int)(p >> 8);
    }

    // ---- src side: degree -> dis ----
    hist[t] = 0;
    __syncthreads();
    const int q0 = bukoff_s[b], q1 = bukoff_s[b + 1];
    for (int i = q0 + t; i < q1; i += 256) atomicAdd(&hist[srcbin[i]], 1);
    __syncthreads();
    if (node < N_NODES) dis[node] = rsqrtf((float)hist[t] + 1.0f);
}

// ---------------------------------------------------------------------------
// GEMM v3 (unchanged, r6-verified): h[r][c] = dis[r]*(b[c] + x[r]·W[c])
// ---------------------------------------------------------------------------
#define BM 32
__global__ __launch_bounds__(256) void gemm_kernel(const float* __restrict__ x,
                                                   const float* __restrict__ W,
                                                   const float* __restrict__ bias,
                                                   const float* __restrict__ dis,
                                                   float* __restrict__ h) {
    __shared__ float4 Ws[128 * 32];  // 64 KiB
    __shared__ float4 Xs[32 * 32];   // 16 KiB

    const int t = threadIdx.x;
    const float4* W4 = (const float4*)W;
#pragma unroll
    for (int i = 0; i < 16; ++i) {
        int j = i * 256 + t;
        int c = j >> 5, kg = j & 31;
        Ws[c * 32 + (kg ^ ((c >> 2) & 7))] = W4[j];
    }
    const int row0 = blockIdx.x * BM;
    const float4* X4 = (const float4*)(x + (size_t)row0 * D);
#pragma unroll
    for (int i = 0; i < 4; ++i) {
        int j = i * 256 + t;
        int r = j >> 5, kg = j & 31;
        Xs[r * 32 + (kg ^ ((r >> 2) & 7))] = X4[j];
    }
    __syncthreads();

    const int rg = t & 7;
    const int cg = t >> 3;
    const int xswz = rg;
    const int wswz = cg & 7;

    float acc[4][4];
#pragma unroll
    for (int a = 0; a < 4; ++a)
#pragma unroll
        for (int c2 = 0; c2 < 4; ++c2) acc[a][c2] = 0.f;

#pragma unroll 2
    for (int kg = 0; kg < 32; ++kg) {
        float4 xv[4], wv[4];
#pragma unroll
        for (int ri = 0; ri < 4; ++ri)
            xv[ri] = Xs[(rg * 4 + ri) * 32 + (kg ^ xswz)];
#pragma unroll
        for (int ci = 0; ci < 4; ++ci)
            wv[ci] = Ws[(cg * 4 + ci) * 32 + (kg ^ wswz)];
#pragma unroll
        for (int ri = 0; ri < 4; ++ri)
#pragma unroll
            for (int ci = 0; ci < 4; ++ci) {
                acc[ri][ci] = fmaf(xv[ri].x, wv[ci].x, acc[ri][ci]);
                acc[ri][ci] = fmaf(xv[ri].y, wv[ci].y, acc[ri][ci]);
                acc[ri][ci] = fmaf(xv[ri].z, wv[ci].z, acc[ri][ci]);
                acc[ri][ci] = fmaf(xv[ri].w, wv[ci].w, acc[ri][ci]);
            }
    }

    const float4 bv = ((const float4*)bias)[cg];
#pragma unroll
    for (int ri = 0; ri < 4; ++ri) {
        int row = row0 + rg * 4 + ri;
        float dv = dis[row];
        float4 o;
        o.x = dv * (acc[ri][0] + bv.x);
        o.y = dv * (acc[ri][1] + bv.y);
        o.z = dv * (acc[ri][2] + bv.z);
        o.w = dv * (acc[ri][3] + bv.w);
        ((float4*)(h + (size_t)row * D))[cg] = o;
    }
}

// ---------------------------------------------------------------------------
// gather (unchanged, r6-verified): one wave per dst node; half-wave pairing.
// ---------------------------------------------------------------------------
__global__ __launch_bounds__(256) void gather_kernel(const int* __restrict__ sorted,
                                                     const int* __restrict__ off,
                                                     const float* __restrict__ dis,
                                                     const float* __restrict__ h,
                                                     float* __restrict__ out) {
    const int node = blockIdx.x * 4 + (threadIdx.x >> 6);
    const int lane = threadIdx.x & 63;
    if (node >= N_NODES) return;
    const int half = lane >> 5;
    const int l32  = lane & 31;

    const int n0 = off[node], n1 = off[node + 1];
    float4 a0 = {0,0,0,0}, a1 = {0,0,0,0}, a2 = {0,0,0,0}, a3 = {0,0,0,0};
    int e = n0;
    for (; e + 8 <= n1; e += 8) {
        int s0 = sorted[e + 0 + half];
        int s1 = sorted[e + 2 + half];
        int s2 = sorted[e + 4 + half];
        int s3 = sorted[e + 6 + half];
        float4 v0 = ((const float4*)(h + (size_t)s0 * D))[l32];
        float4 v1 = ((const float4*)(h + (size_t)s1 * D))[l32];
        float4 v2 = ((const float4*)(h + (size_t)s2 * D))[l32];
        float4 v3 = ((const float4*)(h + (size_t)s3 * D))[l32];
        a0.x += v0.x; a0.y += v0.y; a0.z += v0.z; a0.w += v0.w;
        a1.x += v1.x; a1.y += v1.y; a1.z += v1.z; a1.w += v1.w;
        a2.x += v2.x; a2.y += v2.y; a2.z += v2.z; a2.w += v2.w;
        a3.x += v3.x; a3.y += v3.y; a3.z += v3.z; a3.w += v3.w;
    }
    for (; e + 2 <= n1; e += 2) {
        int s = sorted[e + half];
        float4 v = ((const float4*)(h + (size_t)s * D))[l32];
        a0.x += v.x; a0.y += v.y; a0.z += v.z; a0.w += v.w;
    }
    if (e < n1) {
        int s = sorted[e];
        float4 v = ((const float4*)(h + (size_t)s * D))[l32];
        if (half == 0) {
            a0.x += v.x; a0.y += v.y; a0.z += v.z; a0.w += v.w;
        }
    }
    float4 tot;
    tot.x = (a0.x + a1.x) + (a2.x + a3.x);
    tot.y = (a0.y + a1.y) + (a2.y + a3.y);
    tot.z = (a0.z + a1.z) + (a2.z + a3.z);
    tot.w = (a0.w + a1.w) + (a2.w + a3.w);
    tot.x += __shfl_xor(tot.x, 32);
    tot.y += __shfl_xor(tot.y, 32);
    tot.z += __shfl_xor(tot.z, 32);
    tot.w += __shfl_xor(tot.w, 32);

    if (half == 0) {
        const float dd = dis[node];
        float4 hd = ((const float4*)(h + (size_t)node * D))[l32];
        float4 o;
        o.x = fmaxf(dd * (tot.x + hd.x), 0.f) * 0.125f;
        o.y = fmaxf(dd * (tot.y + hd.y), 0.f) * 0.125f;
        o.z = fmaxf(dd * (tot.z + hd.z), 0.f) * 0.125f;
        o.w = fmaxf(dd * (tot.w + hd.w), 0.f) * 0.125f;
        ((float4*)(out + (size_t)node * D))[l32] = o;
    }
}

extern "C" void kernel_launch(void* const* d_in, const int* in_sizes, int n_in,
                              void* d_out, int out_size, void* d_ws, size_t ws_size,
                              hipStream_t stream) {
    const float* x  = (const float*)d_in[0];
    const int*   ei = (const int*)d_in[1];   // [2, E] int32
    const float* W  = (const float*)d_in[2];
    const float* b  = (const float*)d_in[3];
    float* out = (float*)d_out;

    // workspace layout (~66.5 MB)
    float*        h        = (float*)d_ws;                    // N*D floats
    float*        dis      = h + (size_t)N_NODES * D;         // N
    int*          off      = (int*)(dis + N_NODES);           // N+1
    int*          sorted   = off + N_NODES + 1;               // E
    unsigned int* dstbin   = (unsigned int*)(sorted + N_EDGES);       // E
    unsigned char* srcbin  = (unsigned char*)(dstbin + N_EDGES);      // E bytes
    int*          bukcnt_d = (int*)(srcbin + N_EDGES);        // 392
    int*          bukcnt_s = bukcnt_d + NBUK + 1;             // 392
    int*          bukoff_d = bukcnt_s + NBUK + 1;             // 392
    int*          bukoff_s = bukoff_d + NBUK + 1;             // 392
    int*          bukcur_d = bukoff_s + NBUK + 1;             // 392
    int*          bukcur_s = bukcur_d + NBUK + 1;             // 392

    hipMemsetAsync(bukcnt_d, 0, 2 * (NBUK + 1) * sizeof(int), stream);

    bin_count_kernel<<<NB_E, 256, 0, stream>>>(ei, bukcnt_d, bukcnt_s);
    bukscan_kernel<<<1, 512, 0, stream>>>(bukcnt_d, bukcnt_s, bukoff_d, bukoff_s,
                                          bukcur_d, bukcur_s, off);
    bin_scatter_kernel<<<NB_E, 256, 0, stream>>>(ei, bukcur_d, bukcur_s, dstbin, srcbin);
    bucket_build_kernel<<<NBUK, 256, 0, stream>>>(dstbin, srcbin, bukoff_d, bukoff_s,
                                                  off, sorted, dis);

    gemm_kernel<<<N_NODES / BM, 256, 0, stream>>>(x, W, b, dis, h);

    gather_kernel<<<(N_NODES + 3) / 4, 256, 0, stream>>>(sorted, off, dis, h, out);
}

// Round 8
// 300.494 us; speedup vs baseline: 5.7313x; 1.1700x over previous
//
#include <hip/hip_runtime.h>
#include <hip/hip_bf16.h>
#include <hip/hip_fp16.h>

#define N_NODES 100000
#define N_EDGES 1600000
#define D 128
#define NBUK 391                 // ceil(N_NODES / 256); bucket = 256 nodes
#define EPB 8192                 // edges per block in binning passes
#define NB_E ((N_EDGES + EPB - 1) / EPB)   // 196

// ---------------------------------------------------------------------------
// bin_count: per-block LDS histograms of src/dst BUCKET (node>>8), flushed
// with one global atomic per (block,bucket).
// ---------------------------------------------------------------------------
__global__ __launch_bounds__(256) void bin_count_kernel(const int* __restrict__ ei,
                                                        int* __restrict__ bukcnt_d,
                                                        int* __restrict__ bukcnt_s) {
    __shared__ int cd[NBUK], cs[NBUK];
    const int t = threadIdx.x;
    for (int b = t; b < NBUK; b += 256) { cd[b] = 0; cs[b] = 0; }
    __syncthreads();
    const int e0 = blockIdx.x * EPB;
#pragma unroll
    for (int i = 0; i < EPB / 256; ++i) {
        int e = e0 + i * 256 + t;
        if (e < N_EDGES) {
            atomicAdd(&cs[ei[e] >> 8], 1);
            atomicAdd(&cd[ei[N_EDGES + e] >> 8], 1);
        }
    }
    __syncthreads();
    for (int b = t; b < NBUK; b += 256) {
        if (cd[b]) atomicAdd(&bukcnt_d[b], cd[b]);
        if (cs[b]) atomicAdd(&bukcnt_s[b], cs[b]);
    }
}

// ---------------------------------------------------------------------------
// bukscan: single-block exclusive scan of both 391-entry bucket-count arrays.
// ---------------------------------------------------------------------------
__global__ __launch_bounds__(512) void bukscan_kernel(const int* __restrict__ bukcnt_d,
                                                      const int* __restrict__ bukcnt_s,
                                                      int* __restrict__ bukoff_d,
                                                      int* __restrict__ bukoff_s,
                                                      int* __restrict__ bukcur_d,
                                                      int* __restrict__ bukcur_s,
                                                      int* __restrict__ off) {
    __shared__ int sd[512], ss[512];
    const int t = threadIdx.x;
    sd[t] = (t < NBUK) ? bukcnt_d[t] : 0;
    ss[t] = (t < NBUK) ? bukcnt_s[t] : 0;
    __syncthreads();
    for (int o = 1; o < 512; o <<= 1) {
        int vd = (t >= o) ? sd[t - o] : 0;
        int vs = (t >= o) ? ss[t - o] : 0;
        __syncthreads();
        sd[t] += vd; ss[t] += vs;
        __syncthreads();
    }
    if (t <= NBUK) {
        int od = (t == 0) ? 0 : sd[t - 1];
        int os = (t == 0) ? 0 : ss[t - 1];
        bukoff_d[t] = od;
        bukoff_s[t] = os;
        if (t < NBUK) { bukcur_d[t] = od; bukcur_s[t] = os; }
    }
    if (t == 0) off[N_NODES] = N_EDGES;
}

// ---------------------------------------------------------------------------
// bin_scatter: recount locally, reserve contiguous per-bucket ranges, write
// edges into bucket bins. dstbin packs (src<<8)|dst_local; srcbin = src_local.
// ---------------------------------------------------------------------------
__global__ __launch_bounds__(256) void bin_scatter_kernel(const int* __restrict__ ei,
                                                          int* __restrict__ bukcur_d,
                                                          int* __restrict__ bukcur_s,
                                                          unsigned int* __restrict__ dstbin,
                                                          unsigned char* __restrict__ srcbin) {
    __shared__ int cd[NBUK], cs[NBUK];
    __shared__ int bd[NBUK], bs[NBUK];
    const int t = threadIdx.x;
    for (int b = t; b < NBUK; b += 256) { cd[b] = 0; cs[b] = 0; }
    __syncthreads();
    const int e0 = blockIdx.x * EPB;
#pragma unroll
    for (int i = 0; i < EPB / 256; ++i) {
        int e = e0 + i * 256 + t;
        if (e < N_EDGES) {
            atomicAdd(&cs[ei[e] >> 8], 1);
            atomicAdd(&cd[ei[N_EDGES + e] >> 8], 1);
        }
    }
    __syncthreads();
    for (int b = t; b < NBUK; b += 256) {
        bd[b] = cd[b] ? atomicAdd(&bukcur_d[b], cd[b]) : 0;
        bs[b] = cs[b] ? atomicAdd(&bukcur_s[b], cs[b]) : 0;
        cd[b] = 0; cs[b] = 0;
    }
    __syncthreads();
#pragma unroll
    for (int i = 0; i < EPB / 256; ++i) {
        int e = e0 + i * 256 + t;
        if (e < N_EDGES) {
            int s = ei[e];
            int d = ei[N_EDGES + e];
            int p1 = bd[d >> 8] + atomicAdd(&cd[d >> 8], 1);
            dstbin[p1] = ((unsigned)s << 8) | (unsigned)(d & 255);
            int p2 = bs[s >> 8] + atomicAdd(&cs[s >> 8], 1);
            srcbin[p2] = (unsigned char)(s & 255);
        }
    }
}

// ---------------------------------------------------------------------------
// bucket_build: one block per bucket (256 nodes): LDS hist -> scan -> off[],
// LDS-cursor scatter into sorted[]; src-side hist -> dis = rsqrt(cnt+1).
// ---------------------------------------------------------------------------
__global__ __launch_bounds__(256) void bucket_build_kernel(const unsigned int* __restrict__ dstbin,
                                                           const unsigned char* __restrict__ srcbin,
                                                           const int* __restrict__ bukoff_d,
                                                           const int* __restrict__ bukoff_s,
                                                           int* __restrict__ off,
                                                           int* __restrict__ sorted,
                                                           float* __restrict__ dis) {
    __shared__ int hist[256];
    __shared__ int scn[256];
    __shared__ int cur[256];
    const int t = threadIdx.x, b = blockIdx.x;
    const int node = b * 256 + t;

    const int s0 = bukoff_d[b], s1 = bukoff_d[b + 1];
    hist[t] = 0;
    __syncthreads();
    for (int i = s0 + t; i < s1; i += 256) atomicAdd(&hist[dstbin[i] & 255], 1);
    __syncthreads();
    scn[t] = hist[t];
    __syncthreads();
    for (int o = 1; o < 256; o <<= 1) {
        int v = (t >= o) ? scn[t - o] : 0;
        __syncthreads();
        scn[t] += v;
        __syncthreads();
    }
    const int mybase = s0 + ((t == 0) ? 0 : scn[t - 1]);
    if (node < N_NODES) off[node] = mybase;
    cur[t] = mybase;
    __syncthreads();
    for (int i = s0 + t; i < s1; i += 256) {
        unsigned p = dstbin[i];
        int pos = atomicAdd(&cur[p & 255], 1);
        sorted[pos] = (int)(p >> 8);
    }

    hist[t] = 0;
    __syncthreads();
    const int q0 = bukoff_s[b], q1 = bukoff_s[b + 1];
    for (int i = q0 + t; i < q1; i += 256) atomicAdd(&hist[srcbin[i]], 1);
    __syncthreads();
    if (node < N_NODES) dis[node] = rsqrtf((float)hist[t] + 1.0f);
}

// ---------------------------------------------------------------------------
// GEMM v3 + fp16 epilogue: hh[r][c] = (half) dis[r]*(b[c] + x[r]·W[c])
// fp16 h halves gather traffic; error ~4e-6 at output (see journal).
// ---------------------------------------------------------------------------
#define BM 32
__global__ __launch_bounds__(256) void gemm_kernel(const float* __restrict__ x,
                                                   const float* __restrict__ W,
                                                   const float* __restrict__ bias,
                                                   const float* __restrict__ dis,
                                                   __half* __restrict__ hh) {
    __shared__ float4 Ws[128 * 32];  // 64 KiB
    __shared__ float4 Xs[32 * 32];   // 16 KiB

    const int t = threadIdx.x;
    const float4* W4 = (const float4*)W;
#pragma unroll
    for (int i = 0; i < 16; ++i) {
        int j = i * 256 + t;
        int c = j >> 5, kg = j & 31;
        Ws[c * 32 + (kg ^ ((c >> 2) & 7))] = W4[j];
    }
    const int row0 = blockIdx.x * BM;
    const float4* X4 = (const float4*)(x + (size_t)row0 * D);
#pragma unroll
    for (int i = 0; i < 4; ++i) {
        int j = i * 256 + t;
        int r = j >> 5, kg = j & 31;
        Xs[r * 32 + (kg ^ ((r >> 2) & 7))] = X4[j];
    }
    __syncthreads();

    const int rg = t & 7;
    const int cg = t >> 3;
    const int xswz = rg;
    const int wswz = cg & 7;

    float acc[4][4];
#pragma unroll
    for (int a = 0; a < 4; ++a)
#pragma unroll
        for (int c2 = 0; c2 < 4; ++c2) acc[a][c2] = 0.f;

#pragma unroll 2
    for (int kg = 0; kg < 32; ++kg) {
        float4 xv[4], wv[4];
#pragma unroll
        for (int ri = 0; ri < 4; ++ri)
            xv[ri] = Xs[(rg * 4 + ri) * 32 + (kg ^ xswz)];
#pragma unroll
        for (int ci = 0; ci < 4; ++ci)
            wv[ci] = Ws[(cg * 4 + ci) * 32 + (kg ^ wswz)];
#pragma unroll
        for (int ri = 0; ri < 4; ++ri)
#pragma unroll
            for (int ci = 0; ci < 4; ++ci) {
                acc[ri][ci] = fmaf(xv[ri].x, wv[ci].x, acc[ri][ci]);
                acc[ri][ci] = fmaf(xv[ri].y, wv[ci].y, acc[ri][ci]);
                acc[ri][ci] = fmaf(xv[ri].z, wv[ci].z, acc[ri][ci]);
                acc[ri][ci] = fmaf(xv[ri].w, wv[ci].w, acc[ri][ci]);
            }
    }

    const float4 bv = ((const float4*)bias)[cg];
#pragma unroll
    for (int ri = 0; ri < 4; ++ri) {
        int row = row0 + rg * 4 + ri;
        float dv = dis[row];
        __half2 p0 = __floats2half2_rn(dv * (acc[ri][0] + bv.x), dv * (acc[ri][1] + bv.y));
        __half2 p1 = __floats2half2_rn(dv * (acc[ri][2] + bv.z), dv * (acc[ri][3] + bv.w));
        uint2 u;
        u.x = *(unsigned int*)&p0;
        u.y = *(unsigned int*)&p1;
        ((uint2*)(hh + (size_t)row * D))[cg] = u;   // cols cg*4..cg*4+3
    }
}

// ---------------------------------------------------------------------------
// gather (fp16 h): one wave per dst node, half-wave row pairing; lane reads
// uint2 = 4 halfs (8B) -> 256B per row. fp32 accumulate, fp32 output.
// ---------------------------------------------------------------------------
__global__ __launch_bounds__(256) void gather_kernel(const int* __restrict__ sorted,
                                                     const int* __restrict__ off,
                                                     const float* __restrict__ dis,
                                                     const __half* __restrict__ hh,
                                                     float* __restrict__ out) {
    const int node = blockIdx.x * 4 + (threadIdx.x >> 6);
    const int lane = threadIdx.x & 63;
    if (node >= N_NODES) return;
    const int half = lane >> 5;
    const int l32  = lane & 31;

    const int n0 = off[node], n1 = off[node + 1];
    float4 a0 = {0,0,0,0}, a1 = {0,0,0,0}, a2 = {0,0,0,0}, a3 = {0,0,0,0};

#define ACC(A, V) {                                                   \
        __half2 q0 = *(__half2*)&(V).x, q1 = *(__half2*)&(V).y;       \
        float2 f0 = __half22float2(q0), f1 = __half22float2(q1);      \
        (A).x += f0.x; (A).y += f0.y; (A).z += f1.x; (A).w += f1.y; }

    int e = n0;
    for (; e + 8 <= n1; e += 8) {
        int s0 = sorted[e + 0 + half];
        int s1 = sorted[e + 2 + half];
        int s2 = sorted[e + 4 + half];
        int s3 = sorted[e + 6 + half];
        uint2 v0 = ((const uint2*)(hh + (size_t)s0 * D))[l32];
        uint2 v1 = ((const uint2*)(hh + (size_t)s1 * D))[l32];
        uint2 v2 = ((const uint2*)(hh + (size_t)s2 * D))[l32];
        uint2 v3 = ((const uint2*)(hh + (size_t)s3 * D))[l32];
        ACC(a0, v0); ACC(a1, v1); ACC(a2, v2); ACC(a3, v3);
    }
    for (; e + 2 <= n1; e += 2) {
        int s = sorted[e + half];
        uint2 v = ((const uint2*)(hh + (size_t)s * D))[l32];
        ACC(a0, v);
    }
    if (e < n1) {
        int s = sorted[e];
        uint2 v = ((const uint2*)(hh + (size_t)s * D))[l32];
        if (half == 0) ACC(a0, v);
    }
#undef ACC

    float4 tot;
    tot.x = (a0.x + a1.x) + (a2.x + a3.x);
    tot.y = (a0.y + a1.y) + (a2.y + a3.y);
    tot.z = (a0.z + a1.z) + (a2.z + a3.z);
    tot.w = (a0.w + a1.w) + (a2.w + a3.w);
    tot.x += __shfl_xor(tot.x, 32);
    tot.y += __shfl_xor(tot.y, 32);
    tot.z += __shfl_xor(tot.z, 32);
    tot.w += __shfl_xor(tot.w, 32);

    if (half == 0) {
        const float dd = dis[node];
        uint2 vd = ((const uint2*)(hh + (size_t)node * D))[l32];
        __half2 q0 = *(__half2*)&vd.x, q1 = *(__half2*)&vd.y;
        float2 f0 = __half22float2(q0), f1 = __half22float2(q1);
        float4 o;
        o.x = fmaxf(dd * (tot.x + f0.x), 0.f) * 0.125f;
        o.y = fmaxf(dd * (tot.y + f0.y), 0.f) * 0.125f;
        o.z = fmaxf(dd * (tot.z + f1.x), 0.f) * 0.125f;
        o.w = fmaxf(dd * (tot.w + f1.y), 0.f) * 0.125f;
        ((float4*)(out + (size_t)node * D))[l32] = o;
    }
}

extern "C" void kernel_launch(void* const* d_in, const int* in_sizes, int n_in,
                              void* d_out, int out_size, void* d_ws, size_t ws_size,
                              hipStream_t stream) {
    const float* x  = (const float*)d_in[0];
    const int*   ei = (const int*)d_in[1];   // [2, E] int32
    const float* W  = (const float*)d_in[2];
    const float* b  = (const float*)d_in[3];
    float* out = (float*)d_out;

    // workspace layout (~41 MB)
    __half*       hh       = (__half*)d_ws;                   // N*D halfs (25.6 MB)
    float*        dis      = (float*)(hh + (size_t)N_NODES * D); // N
    int*          off      = (int*)(dis + N_NODES);           // N+1
    int*          sorted   = off + N_NODES + 1;               // E
    unsigned int* dstbin   = (unsigned int*)(sorted + N_EDGES);     // E
    unsigned char* srcbin  = (unsigned char*)(dstbin + N_EDGES);    // E bytes
    int*          bukcnt_d = (int*)(srcbin + N_EDGES);        // 392
    int*          bukcnt_s = bukcnt_d + NBUK + 1;             // 392
    int*          bukoff_d = bukcnt_s + NBUK + 1;             // 392
    int*          bukoff_s = bukoff_d + NBUK + 1;             // 392
    int*          bukcur_d = bukoff_s + NBUK + 1;             // 392
    int*          bukcur_s = bukcur_d + NBUK + 1;             // 392

    hipMemsetAsync(bukcnt_d, 0, 2 * (NBUK + 1) * sizeof(int), stream);

    bin_count_kernel<<<NB_E, 256, 0, stream>>>(ei, bukcnt_d, bukcnt_s);
    bukscan_kernel<<<1, 512, 0, stream>>>(bukcnt_d, bukcnt_s, bukoff_d, bukoff_s,
                                          bukcur_d, bukcur_s, off);
    bin_scatter_kernel<<<NB_E, 256, 0, stream>>>(ei, bukcur_d, bukcur_s, dstbin, srcbin);
    bucket_build_kernel<<<NBUK, 256, 0, stream>>>(dstbin, srcbin, bukoff_d, bukoff_s,
                                                  off, sorted, dis);

    gemm_kernel<<<N_NODES / BM, 256, 0, stream>>>(x, W, b, dis, hh);

    gather_kernel<<<(N_NODES + 3) / 4, 256, 0, stream>>>(sorted, off, dis, hh, out);
}